// Round 12
// baseline (569.025 us; speedup 1.0000x reference)
//
#include <hip/hip_runtime.h>
#include <hip/hip_fp16.h>

// DAG phenotype evaluation: sentinel dataflow + watermark + static ownership
// + prefetch-under-poll + distributed counters + DECOUPLED FLAT POLL (r12).
//
// Round-11 analysis: runtime ~= DAG critical path (~e*K*ln(N/N_IN) ~ 400
// hops) x publish->detect latency (~1.3 us). The poll's first retry was
// paying an extra ~0.4-0.7 us because __hip_atomic_load reloads forced a
// compiler vmcnt(0) that ALSO drained the 33-deep prefetch gather stream.
// Fix: poll retries use FLAT loads (count in BOTH vmcnt and lgkmcnt) and
// wait with s_waitcnt lgkmcnt(0), which retires ONLY the flat poll loads
// (+ fast SMEM) - never the global-load prefetch stream. First 4 retries
// spin tight; s_sleep(1) backoff after (polled set is 1-3 rows, bounded).
//
// Structure (proven r10/r11):
//   - wave w of NW=2048 owns nodes N_IN + w + t*NW (48 rounds); 512 blocks
//     x 4 waves, 2 blocks/CU, 0 LDS -> all waves resident.
//   - per iteration ONE top vmcnt(0) (drains prefetch issued an iter ago,
//     prev publish stores, prev sub atomic) + the dependency poll.
//   - preds < WM (stale lower bound = safe): PLAIN cached loads (L2);
//     preds >= WM: agent-coherent loads (sc0 sc1) + sentinel poll.
//   - publish: sc0 sc1 write-through store; two-level distributed page
//     counters (32 sub-lines/page) -> subs_done -> WM CAS; WM replicated
//     over 32 lines (monotone, races leave lower = safe value).
//
// vals[N_NODES][64]: packed half2(b, b+64), 256 B/row; SENTW = NaN|NaN =
// "not ready" (no real value is NaN: inputs finite, outputs relu>=0).
//
// Deadlock-freedom: all waves resident; waves process own nodes in
// increasing order; lowest uncomputed node m: its owner's current node
// j <= m has all preds < j computed, so its poll terminates -> induction
// reaches m. WM lag cannot deadlock (polls are correct with WM == 0).

#define N_NODES 100000
#define N_IN    1024
#define N_OUT   1024
#define FAN_IN  32
#define NPAIR   64              // BATCH/2 packed slots per row
#define N_TODO  (N_NODES - N_IN)
#define SENTW   0xFFFFFFFFu
#define NW      2048            // static owner waves
#define NBLK    (NW / 4)        // 512 blocks
#define PGSZ    1024
#define PGSHIFT 10
#define NPAGES  ((N_TODO + PGSZ - 1) / PGSZ)   // 97
#define NSUB    32              // sub-counter lines per page
#define WMREP   32              // WM replica lines

// ws layout (bytes), every counter word on its own 256-B line:
//   [4096]    wm[32 replicas], stride 256 B (replica 0 = master)
//   [16384]   subs_done[97], stride 256 B
//   [65536]   sub_cnt[97*32], stride 256 B
//   [860160]  vals (25.6 MB)
#define OFS_WM    4096
#define OFS_SD    16384
#define OFS_SUB   65536
#define OFS_VALS  860160
#define LSTRIDE   64            // ints per 256-B line

__device__ __forceinline__ int subq(int pg) {
    return min(PGSZ, N_TODO - (pg << PGSHIFT)) >> 5;   // 32, last page 21
}

__global__ __launch_bounds__(256) void init_kernel(const float* __restrict__ x,
                                                   unsigned* __restrict__ vals,
                                                   int* __restrict__ wm,
                                                   int* __restrict__ subs_done,
                                                   int* __restrict__ sub_cnt) {
    const int tid = blockIdx.x * blockDim.x + threadIdx.x;
    if (tid < WMREP)         wm[tid * LSTRIDE] = 0;
    if (tid < NPAGES)        subs_done[tid * LSTRIDE] = 0;
    if (tid < NPAGES * NSUB) sub_cnt[tid * LSTRIDE] = 0;
    if (tid < N_IN * NPAIR) {
        const int i = tid >> 6;
        const int b = tid & 63;
        __half2 h2 = __floats2half2_rn(x[b * N_IN + i], x[(b + 64) * N_IN + i]);
        vals[i * NPAIR + b] = *reinterpret_cast<unsigned*>(&h2);
    }
    uint4* p = (uint4*)(vals + (size_t)N_IN * NPAIR);
    const int total = N_TODO * NPAIR / 4;
    const uint4 s4 = make_uint4(SENTW, SENTW, SENTW, SENTW);
    for (int t = tid; t < total; t += gridDim.x * blockDim.x)
        p[t] = s4;
}

__device__ __forceinline__ void wm_advance(int* wm, int* subs_done) {
    for (;;) {   // advance master WM over all consecutively-complete pages
        int cur = __hip_atomic_load(wm, __ATOMIC_RELAXED, __HIP_MEMORY_SCOPE_AGENT);
        if (cur >= NPAGES) break;
        int sd = __hip_atomic_load(subs_done + (size_t)cur * LSTRIDE,
                                   __ATOMIC_RELAXED, __HIP_MEMORY_SCOPE_AGENT);
        if (sd < NSUB) break;
        int expected = cur;
        __hip_atomic_compare_exchange_strong(wm, &expected, cur + 1,
                                             __ATOMIC_RELAXED, __ATOMIC_RELAXED,
                                             __HIP_MEMORY_SCOPE_AGENT);
    }
    int fin = __hip_atomic_load(wm, __ATOMIC_RELAXED, __HIP_MEMORY_SCOPE_AGENT);
    for (int r = 1; r < WMREP; ++r)
        __hip_atomic_store(wm + (size_t)r * LSTRIDE, fin,
                           __ATOMIC_RELAXED, __HIP_MEMORY_SCOPE_AGENT);
}

__global__ __launch_bounds__(256, 2) void dag_kernel(const float* __restrict__ weights,
                                                     const int* __restrict__ in_ids,
                                                     unsigned* __restrict__ vals,
                                                     int* __restrict__ wm,
                                                     int* __restrict__ subs_done,
                                                     int* __restrict__ sub_cnt,
                                                     float* __restrict__ out) {
    const int tid  = threadIdx.x;
    const int lane = tid & 63;
    const int w    = __builtin_amdgcn_readfirstlane(blockIdx.x * 4 + (tid >> 6));
    const int g    = w & (NSUB - 1);                 // sub-counter group
    int* wm_rep    = wm + (size_t)(blockIdx.x & (WMREP - 1)) * LSTRIDE;

    unsigned v[FAN_IN];          // current node's gathered pred values
    unsigned vn[FAN_IN];         // prefetch buffer
    unsigned wmv  = 0;           // asm-loaded wm replica (valid after top drain)
    unsigned cohm = 0, cmn = 0;  // uniform coherent-path bitmasks (cur / next)
    int pend_pg = -1, pend_old = 0;

    int node = N_IN + w;         // first own node

    // prologue: issue gather(first) into vn with wmn = N_IN
    {
        const long wb = (long)node * FAN_IN;
#pragma unroll
        for (int k = 0; k < FAN_IN; ++k) {
            const int id = in_ids[wb + k];
            const unsigned* p = vals + (long)id * NPAIR + lane;
            if (id < N_IN) {
                asm volatile("global_load_dword %0, %1, off"
                             : "=v"(vn[k]) : "v"(p));
            } else {
                asm volatile("global_load_dword %0, %1, off sc0 sc1"
                             : "=v"(vn[k]) : "v"(p));
                cmn |= 1u << k;
            }
        }
        asm volatile("global_load_dword %0, %1, off sc0 sc1"
                     : "=v"(wmv) : "v"(wm_rep));
    }

    for (;;) {
        // single wait: drains prefetch(vn)+WM (issued one iter ago), prev
        // publish stores, and the sub atomic before that.
        asm volatile("s_waitcnt vmcnt(0)" ::: "memory");
        __builtin_amdgcn_sched_barrier(0);

        // promote prefetch buffer to working buffer
#pragma unroll
        for (int k = 0; k < FAN_IN; ++k) v[k] = vn[k];
        cohm = cmn;

        // deferred sub-fill check (atomic issued last iter, result drained)
        if (pend_pg >= 0) {
            if (lane == 0 && pend_old + 1 == subq(pend_pg)) {
                int sd = __hip_atomic_fetch_add(subs_done + (size_t)pend_pg * LSTRIDE, 1,
                                                __ATOMIC_RELAXED, __HIP_MEMORY_SCOPE_AGENT);
                if (sd + 1 == NSUB) wm_advance(wm, subs_done);
            }
            pend_pg = -1;
        }
        // issue sub atomic for PREVIOUS own node (its stores are drained)
        if (node - NW >= N_IN) {
            const int ppg = (node - NW - N_IN) >> PGSHIFT;
            if (lane == 0)
                pend_old = __hip_atomic_fetch_add(
                    sub_cnt + ((size_t)ppg * NSUB + g) * LSTRIDE, 1,
                    __ATOMIC_RELAXED, __HIP_MEMORY_SCOPE_AGENT);
            pend_pg = ppg;
        }

        // WM for classifying the NEXT node's gather (one iter stale = safe)
        const int wmn = __builtin_amdgcn_readfirstlane((int)(N_IN + (wmv << PGSHIFT)));

        // issue prefetch gather(next) into vn NOW — hides under poll(cur)
        const int nxt = node + NW;
        cmn = 0;
        if (nxt < N_NODES) {
            const long wbn = (long)nxt * FAN_IN;
#pragma unroll
            for (int k = 0; k < FAN_IN; ++k) {
                const int id = in_ids[wbn + k];
                const unsigned* p = vals + (long)id * NPAIR + lane;
                if (id < wmn) {
                    asm volatile("global_load_dword %0, %1, off"
                                 : "=v"(vn[k]) : "v"(p));
                } else {
                    asm volatile("global_load_dword %0, %1, off sc0 sc1"
                                 : "=v"(vn[k]) : "v"(p));
                    cmn |= 1u << k;
                }
            }
            asm volatile("global_load_dword %0, %1, off sc0 sc1"
                         : "=v"(wmv) : "v"(wm_rep));
        }

        const long wb = (long)node * FAN_IN;

        // sentinel poll over the coherent subset. Retries use FLAT loads +
        // lgkmcnt(0): waits ONLY the poll loads, not the prefetch stream.
        unsigned need = cohm;
        int spin = 0;
        while (need) {
            unsigned got = 0;
#pragma unroll
            for (int k = 0; k < FAN_IN; ++k)
                if ((need >> k) & 1u)
                    if (__all(v[k] != SENTW)) got |= 1u << k;
            need &= ~got;
            if (!need) break;
            if (++spin > 4) __builtin_amdgcn_s_sleep(1);
#pragma unroll
            for (int k = 0; k < FAN_IN; ++k)
                if ((need >> k) & 1u) {
                    const unsigned* p = vals + (long)in_ids[wb + k] * NPAIR + lane;
                    asm volatile("flat_load_dword %0, %1 sc0 sc1"
                                 : "=v"(v[k]) : "v"(p));
                }
            asm volatile("s_waitcnt lgkmcnt(0)" ::: "memory");
            __builtin_amdgcn_sched_barrier(0);
        }

        // dot + relu in fp32 (weights uniform -> SGPR operand)
        float acc0 = 0.f, acc1 = 0.f;
#pragma unroll
        for (int k = 0; k < FAN_IN; ++k) {
            const float  wk = weights[wb + k];
            const __half2 h2 = *reinterpret_cast<const __half2*>(&v[k]);
            const float2  f  = __half22float2(h2);
            acc0 = fmaf(wk, f.x, acc0);
            acc1 = fmaf(wk, f.y, acc1);
        }
        acc0 = fmaxf(acc0, 0.f);
        acc1 = fmaxf(acc1, 0.f);

        // publish (agent-coherent write-through store; drained at next top)
        __half2 hr = __floats2half2_rn(acc0, acc1);
        const unsigned ow = *reinterpret_cast<const unsigned*>(&hr);
        unsigned* orow = vals + (long)node * NPAIR + lane;
        asm volatile("global_store_dword %0, %1, off sc0 sc1"
                     :: "v"(orow), "v"(ow));

        // output-layer scatter
        if (node >= N_NODES - N_OUT) {
            const int jo = node - (N_NODES - N_OUT);
            out[lane * N_OUT + jo]        = acc0;
            out[(lane + 64) * N_OUT + jo] = acc1;
        }

        if (nxt >= N_NODES) break;
        node = nxt;
    }

    // epilogue: drain last publish, flush pending + last node's count
    asm volatile("s_waitcnt vmcnt(0)" ::: "memory");
    if (lane == 0) {
        if (pend_pg >= 0 && pend_old + 1 == subq(pend_pg)) {
            int sd = __hip_atomic_fetch_add(subs_done + (size_t)pend_pg * LSTRIDE, 1,
                                            __ATOMIC_RELAXED, __HIP_MEMORY_SCOPE_AGENT);
            if (sd + 1 == NSUB) wm_advance(wm, subs_done);
        }
        const int pg = (node - N_IN) >> PGSHIFT;
        int old = __hip_atomic_fetch_add(sub_cnt + ((size_t)pg * NSUB + g) * LSTRIDE, 1,
                                         __ATOMIC_RELAXED, __HIP_MEMORY_SCOPE_AGENT);
        if (old + 1 == subq(pg)) {
            int sd = __hip_atomic_fetch_add(subs_done + (size_t)pg * LSTRIDE, 1,
                                            __ATOMIC_RELAXED, __HIP_MEMORY_SCOPE_AGENT);
            if (sd + 1 == NSUB) wm_advance(wm, subs_done);
        }
    }
}

extern "C" void kernel_launch(void* const* d_in, const int* in_sizes, int n_in,
                              void* d_out, int out_size, void* d_ws, size_t ws_size,
                              hipStream_t stream) {
    const float* x       = (const float*)d_in[0];
    const float* weights = (const float*)d_in[1];
    const int*   in_ids  = (const int*)d_in[2];
    float*       out     = (float*)d_out;

    int*      wm       = (int*)((char*)d_ws + OFS_WM);
    int*      subs_done= (int*)((char*)d_ws + OFS_SD);
    int*      sub_cnt  = (int*)((char*)d_ws + OFS_SUB);
    unsigned* vals     = (unsigned*)((char*)d_ws + OFS_VALS);

    init_kernel<<<2048, 256, 0, stream>>>(x, vals, wm, subs_done, sub_cnt);
    dag_kernel<<<NBLK, 256, 0, stream>>>(weights, in_ids, vals,
                                         wm, subs_done, sub_cnt, out);
}

// Round 16
// 472.349 us; speedup vs baseline: 1.2047x; 1.2047x over previous
//
#include <hip/hip_runtime.h>
#include <hip/hip_fp16.h>

// DAG phenotype evaluation: sentinel dataflow + watermark + static ownership
// + prefetch-under-poll + distributed counters (round 16 = r11 code with
// NW=4096).
//
// r11 is the proven-correct structure (525us). r12-r15 all tried to
// micro-optimize the poll/prefetch interaction and all FAILED or regressed:
// the asm "=v" in-flight-load pattern corrupts silently if the allocator
// spills an asm-output register between issue and waitcnt (captures the
// pre-load sentinel -> NaN -> relu 0). So r16 changes ZERO code — only the
// constant NW 2048->4096 (NBLK 512->1024), halving the serial rounds per
// wave (48->24), the same lever that gave -17% at r9->r10.
//
// Residency: 40 VGPR, 0 LDS, 256 thr -> HW capacity 8 blocks/CU; 1024
// blocks = 4/CU -> all 4096 waves resident -> deadlock-freedom induction
// holds (lowest uncomputed node's owner is running; its preds < node are
// complete; its poll terminates).
//
// Structure: wave w of NW owns nodes N_IN + w + t*NW in increasing t.
// Per iteration ONE top vmcnt(0) (drains the 33-load prefetch issued an
// iteration ago, prev publish stores, prev sub atomic) + sentinel poll.
// Preds < WM (stale lower bound = safe): PLAIN cached loads (L2);
// preds >= WM: agent-coherent loads (sc0 sc1) + poll w/ s_sleep backoff.
// Publish: sc0 sc1 write-through store. Two-level distributed page
// counters (32 sub-lines/page; quota 32, last page 21) -> subs_done ->
// WM CAS; WM replicated over 32 lines (monotone; races leave lower=safe).
//
// vals[N_NODES][64]: packed half2(b, b+64), 256 B/row; SENTW = NaN|NaN =
// "not ready" (no real value is NaN: inputs finite, outputs relu>=0).

#define N_NODES 100000
#define N_IN    1024
#define N_OUT   1024
#define FAN_IN  32
#define NPAIR   64
#define N_TODO  (N_NODES - N_IN)
#define SENTW   0xFFFFFFFFu
#define NW      4096
#define NBLK    (NW / 4)        // 1024 blocks
#define PGSZ    1024
#define PGSHIFT 10
#define NPAGES  ((N_TODO + PGSZ - 1) / PGSZ)   // 97
#define NSUB    32
#define WMREP   32

#define OFS_WM    4096
#define OFS_SD    16384
#define OFS_SUB   65536
#define OFS_VALS  860160
#define LSTRIDE   64

__device__ __forceinline__ int subq(int pg) {
    return min(PGSZ, N_TODO - (pg << PGSHIFT)) >> 5;   // 32, last page 21
}

__global__ __launch_bounds__(256) void init_kernel(const float* __restrict__ x,
                                                   unsigned* __restrict__ vals,
                                                   int* __restrict__ wm,
                                                   int* __restrict__ subs_done,
                                                   int* __restrict__ sub_cnt) {
    const int tid = blockIdx.x * blockDim.x + threadIdx.x;
    if (tid < WMREP)         wm[tid * LSTRIDE] = 0;
    if (tid < NPAGES)        subs_done[tid * LSTRIDE] = 0;
    if (tid < NPAGES * NSUB) sub_cnt[tid * LSTRIDE] = 0;
    if (tid < N_IN * NPAIR) {
        const int i = tid >> 6;
        const int b = tid & 63;
        __half2 h2 = __floats2half2_rn(x[b * N_IN + i], x[(b + 64) * N_IN + i]);
        vals[i * NPAIR + b] = *reinterpret_cast<unsigned*>(&h2);
    }
    uint4* p = (uint4*)(vals + (size_t)N_IN * NPAIR);
    const int total = N_TODO * NPAIR / 4;
    const uint4 s4 = make_uint4(SENTW, SENTW, SENTW, SENTW);
    for (int t = tid; t < total; t += gridDim.x * blockDim.x)
        p[t] = s4;
}

__device__ __forceinline__ void wm_advance(int* wm, int* subs_done) {
    for (;;) {   // advance master WM over all consecutively-complete pages
        int cur = __hip_atomic_load(wm, __ATOMIC_RELAXED, __HIP_MEMORY_SCOPE_AGENT);
        if (cur >= NPAGES) break;
        int sd = __hip_atomic_load(subs_done + (size_t)cur * LSTRIDE,
                                   __ATOMIC_RELAXED, __HIP_MEMORY_SCOPE_AGENT);
        if (sd < NSUB) break;
        int expected = cur;
        __hip_atomic_compare_exchange_strong(wm, &expected, cur + 1,
                                             __ATOMIC_RELAXED, __ATOMIC_RELAXED,
                                             __HIP_MEMORY_SCOPE_AGENT);
    }
    int fin = __hip_atomic_load(wm, __ATOMIC_RELAXED, __HIP_MEMORY_SCOPE_AGENT);
    for (int r = 1; r < WMREP; ++r)
        __hip_atomic_store(wm + (size_t)r * LSTRIDE, fin,
                           __ATOMIC_RELAXED, __HIP_MEMORY_SCOPE_AGENT);
}

__global__ __launch_bounds__(256, 2) void dag_kernel(const float* __restrict__ weights,
                                                     const int* __restrict__ in_ids,
                                                     unsigned* __restrict__ vals,
                                                     int* __restrict__ wm,
                                                     int* __restrict__ subs_done,
                                                     int* __restrict__ sub_cnt,
                                                     float* __restrict__ out) {
    const int tid  = threadIdx.x;
    const int lane = tid & 63;
    const int w    = __builtin_amdgcn_readfirstlane(blockIdx.x * 4 + (tid >> 6));
    const int g    = w & (NSUB - 1);                 // sub-counter group
    int* wm_rep    = wm + (size_t)(blockIdx.x & (WMREP - 1)) * LSTRIDE;

    unsigned v[FAN_IN];          // current node's gathered pred values
    unsigned vn[FAN_IN];         // prefetch buffer
    unsigned wmv  = 0;           // asm-loaded wm replica (valid after top drain)
    unsigned cohm = 0, cmn = 0;  // uniform coherent-path bitmasks (cur / next)
    int pend_pg = -1, pend_old = 0;

    int node = N_IN + w;         // first own node

    // prologue: issue gather(first) into vn with wmn = N_IN
    {
        const long wb = (long)node * FAN_IN;
#pragma unroll
        for (int k = 0; k < FAN_IN; ++k) {
            const int id = in_ids[wb + k];
            const unsigned* p = vals + (long)id * NPAIR + lane;
            if (id < N_IN) {
                asm volatile("global_load_dword %0, %1, off"
                             : "=v"(vn[k]) : "v"(p));
            } else {
                asm volatile("global_load_dword %0, %1, off sc0 sc1"
                             : "=v"(vn[k]) : "v"(p));
                cmn |= 1u << k;
            }
        }
        asm volatile("global_load_dword %0, %1, off sc0 sc1"
                     : "=v"(wmv) : "v"(wm_rep));
    }

    for (;;) {
        // single wait: drains prefetch(vn)+WM (issued one iter ago), prev
        // publish stores, and the sub atomic before that.
        asm volatile("s_waitcnt vmcnt(0)" ::: "memory");
        __builtin_amdgcn_sched_barrier(0);

        // promote prefetch buffer to working buffer
#pragma unroll
        for (int k = 0; k < FAN_IN; ++k) v[k] = vn[k];
        cohm = cmn;

        // deferred sub-fill check (atomic issued last iter, result drained)
        if (pend_pg >= 0) {
            if (lane == 0 && pend_old + 1 == subq(pend_pg)) {
                int sd = __hip_atomic_fetch_add(subs_done + (size_t)pend_pg * LSTRIDE, 1,
                                                __ATOMIC_RELAXED, __HIP_MEMORY_SCOPE_AGENT);
                if (sd + 1 == NSUB) wm_advance(wm, subs_done);
            }
            pend_pg = -1;
        }
        // issue sub atomic for PREVIOUS own node (its stores are drained)
        if (node - NW >= N_IN) {
            const int ppg = (node - NW - N_IN) >> PGSHIFT;
            if (lane == 0)
                pend_old = __hip_atomic_fetch_add(
                    sub_cnt + ((size_t)ppg * NSUB + g) * LSTRIDE, 1,
                    __ATOMIC_RELAXED, __HIP_MEMORY_SCOPE_AGENT);
            pend_pg = ppg;
        }

        // WM for classifying the NEXT node's gather (one iter stale = safe)
        const int wmn = __builtin_amdgcn_readfirstlane((int)(N_IN + (wmv << PGSHIFT)));

        // issue prefetch gather(next) into vn NOW — hides under poll(cur)
        const int nxt = node + NW;
        cmn = 0;
        if (nxt < N_NODES) {
            const long wbn = (long)nxt * FAN_IN;
#pragma unroll
            for (int k = 0; k < FAN_IN; ++k) {
                const int id = in_ids[wbn + k];
                const unsigned* p = vals + (long)id * NPAIR + lane;
                if (id < wmn) {
                    asm volatile("global_load_dword %0, %1, off"
                                 : "=v"(vn[k]) : "v"(p));
                } else {
                    asm volatile("global_load_dword %0, %1, off sc0 sc1"
                                 : "=v"(vn[k]) : "v"(p));
                    cmn |= 1u << k;
                }
            }
            asm volatile("global_load_dword %0, %1, off sc0 sc1"
                         : "=v"(wmv) : "v"(wm_rep));
        }

        const long wb = (long)node * FAN_IN;

        // sentinel poll over the coherent subset (irreducible dependency wait)
        unsigned need = cohm;
        while (need) {
            unsigned got = 0;
#pragma unroll
            for (int k = 0; k < FAN_IN; ++k)
                if ((need >> k) & 1u)
                    if (__all(v[k] != SENTW)) got |= 1u << k;
            need &= ~got;
            if (!need) break;
            __builtin_amdgcn_s_sleep(1);
#pragma unroll
            for (int k = 0; k < FAN_IN; ++k)
                if ((need >> k) & 1u) {
                    const int id = in_ids[wb + k];
                    v[k] = __hip_atomic_load(vals + (long)id * NPAIR + lane,
                                             __ATOMIC_RELAXED,
                                             __HIP_MEMORY_SCOPE_AGENT);
                }
        }

        // dot + relu in fp32 (weights uniform -> SGPR operand)
        float acc0 = 0.f, acc1 = 0.f;
#pragma unroll
        for (int k = 0; k < FAN_IN; ++k) {
            const float  wk = weights[wb + k];
            const __half2 h2 = *reinterpret_cast<const __half2*>(&v[k]);
            const float2  f  = __half22float2(h2);
            acc0 = fmaf(wk, f.x, acc0);
            acc1 = fmaf(wk, f.y, acc1);
        }
        acc0 = fmaxf(acc0, 0.f);
        acc1 = fmaxf(acc1, 0.f);

        // publish (agent-coherent write-through store; drained at next top)
        __half2 hr = __floats2half2_rn(acc0, acc1);
        const unsigned ow = *reinterpret_cast<const unsigned*>(&hr);
        unsigned* orow = vals + (long)node * NPAIR + lane;
        asm volatile("global_store_dword %0, %1, off sc0 sc1"
                     :: "v"(orow), "v"(ow));

        // output-layer scatter
        if (node >= N_NODES - N_OUT) {
            const int jo = node - (N_NODES - N_OUT);
            out[lane * N_OUT + jo]        = acc0;
            out[(lane + 64) * N_OUT + jo] = acc1;
        }

        if (nxt >= N_NODES) break;
        node = nxt;
    }

    // epilogue: drain last publish, flush pending + last node's count
    asm volatile("s_waitcnt vmcnt(0)" ::: "memory");
    if (lane == 0) {
        if (pend_pg >= 0 && pend_old + 1 == subq(pend_pg)) {
            int sd = __hip_atomic_fetch_add(subs_done + (size_t)pend_pg * LSTRIDE, 1,
                                            __ATOMIC_RELAXED, __HIP_MEMORY_SCOPE_AGENT);
            if (sd + 1 == NSUB) wm_advance(wm, subs_done);
        }
        const int pg = (node - N_IN) >> PGSHIFT;
        int old = __hip_atomic_fetch_add(sub_cnt + ((size_t)pg * NSUB + g) * LSTRIDE, 1,
                                         __ATOMIC_RELAXED, __HIP_MEMORY_SCOPE_AGENT);
        if (old + 1 == subq(pg)) {
            int sd = __hip_atomic_fetch_add(subs_done + (size_t)pg * LSTRIDE, 1,
                                            __ATOMIC_RELAXED, __HIP_MEMORY_SCOPE_AGENT);
            if (sd + 1 == NSUB) wm_advance(wm, subs_done);
        }
    }
}

extern "C" void kernel_launch(void* const* d_in, const int* in_sizes, int n_in,
                              void* d_out, int out_size, void* d_ws, size_t ws_size,
                              hipStream_t stream) {
    const float* x       = (const float*)d_in[0];
    const float* weights = (const float*)d_in[1];
    const int*   in_ids  = (const int*)d_in[2];
    float*       out     = (float*)d_out;

    int*      wm       = (int*)((char*)d_ws + OFS_WM);
    int*      subs_done= (int*)((char*)d_ws + OFS_SD);
    int*      sub_cnt  = (int*)((char*)d_ws + OFS_SUB);
    unsigned* vals     = (unsigned*)((char*)d_ws + OFS_VALS);

    init_kernel<<<2048, 256, 0, stream>>>(x, vals, wm, subs_done, sub_cnt);
    // 1024 blocks x 4 waves = NW=4096 static owner waves; 40 VGPR / 0 LDS
    // -> HW capacity 8 blocks/CU, so all 1024 blocks (4/CU) are resident.
    dag_kernel<<<NBLK, 256, 0, stream>>>(weights, in_ids, vals,
                                         wm, subs_done, sub_cnt, out);
}